// Round 3
// baseline (747.346 us; speedup 1.0000x reference)
//
#include <hip/hip_runtime.h>

#define DF 128  // feature dim (D_IN == H == 128)

typedef short bf16x8 __attribute__((ext_vector_type(8)));
typedef float f32x4 __attribute__((ext_vector_type(4)));

// ---------- helpers ----------
__device__ __forceinline__ float4 f4_fma(float4 a, float s, float4 acc) {
    acc.x += a.x * s; acc.y += a.y * s; acc.z += a.z * s; acc.w += a.w * s;
    return acc;
}
__device__ __forceinline__ float4 f4_relu(float4 v) {
    v.x = fmaxf(v.x, 0.f); v.y = fmaxf(v.y, 0.f); v.z = fmaxf(v.z, 0.f); v.w = fmaxf(v.w, 0.f);
    return v;
}
__device__ __forceinline__ unsigned short f32_to_bf16_rne(float f) {
    unsigned u = __float_as_uint(f);
    unsigned r = (u + 0x7fffu + ((u >> 16) & 1u)) >> 16;
    return (unsigned short)r;
}
__device__ __forceinline__ float bf16_to_f32(unsigned short h) {
    return __uint_as_float(((unsigned)h) << 16);
}
// split 8 floats into hi/lo bf16 fragments
__device__ __forceinline__ void split8(float4 a, float4 b, bf16x8& hi, bf16x8& lo) {
    float v[8] = {a.x, a.y, a.z, a.w, b.x, b.y, b.z, b.w};
    #pragma unroll
    for (int j = 0; j < 8; ++j) {
        unsigned short h = f32_to_bf16_rne(v[j]);
        hi[j] = (short)h;
        float rem = v[j] - bf16_to_f32(h);
        lo[j] = (short)f32_to_bf16_rne(rem);
    }
}

// ---------- CSR build ----------
__global__ __launch_bounds__(256) void count_kernel(const int* __restrict__ ei, int E,
                                                    int* __restrict__ counts) {
    int e = blockIdx.x * 256 + threadIdx.x;
    if (e < E) atomicAdd(&counts[ei[E + e]], 1);
}

// Phase A: per-block sums of counts (1024 elems per block)
__global__ __launch_bounds__(1024) void scan_partials_kernel(const int* __restrict__ counts, int N,
                                                             int* __restrict__ partials) {
    __shared__ int wsum[16];
    int t = threadIdx.x, lane = t & 63, wid = t >> 6;
    int i = blockIdx.x * 1024 + t;
    int c = (i < N) ? counts[i] : 0;
    #pragma unroll
    for (int off = 32; off > 0; off >>= 1) c += __shfl_xor(c, off, 64);
    if (lane == 0) wsum[wid] = c;
    __syncthreads();
    if (t == 0) {
        int s = 0;
        #pragma unroll
        for (int w = 0; w < 16; ++w) s += wsum[w];
        partials[blockIdx.x] = s;
    }
}

// Phase B: single-block exclusive scan over NB (<=1024) partials; writes total to row_end
__global__ __launch_bounds__(1024) void scan_offsets_kernel(int* __restrict__ partials, int NB,
                                                            int* __restrict__ row_end) {
    __shared__ int wtot[16];
    int t = threadIdx.x, lane = t & 63, wid = t >> 6;
    int c = (t < NB) ? partials[t] : 0;
    int incl = c;
    #pragma unroll
    for (int off = 1; off < 64; off <<= 1) {
        int n = __shfl_up(incl, off, 64);
        if (lane >= off) incl += n;
    }
    if (lane == 63) wtot[wid] = incl;
    __syncthreads();
    int wbase = 0, total = 0;
    #pragma unroll
    for (int w = 0; w < 16; ++w) {
        int v = wtot[w];
        if (w < wid) wbase += v;
        total += v;
    }
    if (t < NB) partials[t] = wbase + incl - c;
    if (t == 0) *row_end = total;
}

// Phase C: local scan + block offset -> row_start/cursor/dis
__global__ __launch_bounds__(1024) void scan_write_kernel(const int* __restrict__ counts, int N,
                                                          const int* __restrict__ partials,
                                                          int* __restrict__ row_start,
                                                          int* __restrict__ cursor,
                                                          float* __restrict__ dis) {
    __shared__ int wtot[16];
    int t = threadIdx.x, lane = t & 63, wid = t >> 6;
    int i = blockIdx.x * 1024 + t;
    int c = (i < N) ? counts[i] : 0;
    int incl = c;
    #pragma unroll
    for (int off = 1; off < 64; off <<= 1) {
        int n = __shfl_up(incl, off, 64);
        if (lane >= off) incl += n;
    }
    if (lane == 63) wtot[wid] = incl;
    __syncthreads();
    int wbase = 0;
    #pragma unroll
    for (int w = 0; w < 16; ++w) {
        int v = wtot[w];
        if (w < wid) wbase += v;
    }
    if (i < N) {
        int excl = partials[blockIdx.x] + wbase + incl - c;
        row_start[i] = excl;
        cursor[i]    = excl;
        dis[i]       = rsqrtf((float)(c + 1));   // +1 self loop
    }
}

__global__ __launch_bounds__(256) void scatter_kernel(const int* __restrict__ ei, int E,
                                                      const float* __restrict__ dis,
                                                      int* __restrict__ cursor,
                                                      int2* __restrict__ edges) {
    int e = blockIdx.x * 256 + threadIdx.x;
    if (e < E) {
        int s = ei[e];
        int d = ei[E + e];
        int pos = atomicAdd(&cursor[d], 1);
        int2 packed;
        packed.x = s;
        packed.y = __float_as_int(dis[s] * dis[d]);
        edges[pos] = packed;
    }
}

// ---------- W fragment prep: Ws[L][128][128] -> hi/lo bf16 fragment planes ----------
// tuple t=(s*8+n)*64+lane holds 8 bf16: elem j <-> W[s*32+4*(lane>>4)+(j&3)+16*(j>>2)][n*16+(lane&15)]
__global__ __launch_bounds__(256) void wprep_kernel(const float* __restrict__ Ws,
                                                    unsigned short* __restrict__ WHg,
                                                    unsigned short* __restrict__ WLg,
                                                    int total) {
    int g = blockIdx.x * 256 + threadIdx.x;
    if (g >= total) return;
    int l = g >> 11;         // layer
    int t = g & 2047;
    int s = t >> 9;
    int n = (t >> 6) & 7;
    int lane = t & 63;
    int kb = s * 32 + ((lane >> 4) << 2);
    int c  = n * 16 + (lane & 15);
    const float* W = Ws + (size_t)l * DF * DF;
    bf16x8 hi, lo;
    #pragma unroll
    for (int j = 0; j < 8; ++j) {
        int k = kb + (j & 3) + ((j >> 2) << 4);
        float w = W[k * DF + c];
        unsigned short h = f32_to_bf16_rne(w);
        hi[j] = (short)h;
        lo[j] = (short)f32_to_bf16_rne(w - bf16_to_f32(h));
    }
    *(bf16x8*)&WHg[(size_t)g * 8] = hi;
    *(bf16x8*)&WLg[(size_t)g * 8] = lo;
}

// ---------- MFMA split-bf16 GEMM: C[M,128] = (relu?relu(A):A) @ W ----------
// 256 threads = 4 waves; each wave computes 32 rows x 128 cols. B fragments from
// pre-converted global planes (L2-resident, coalesced 16B/lane).
#define GBM 128
__global__ __launch_bounds__(256) void gemm_mfma(const float* __restrict__ A,
                                                 const unsigned short* __restrict__ WHg,
                                                 const unsigned short* __restrict__ WLg,
                                                 float* __restrict__ C,
                                                 int M, int relu) {
    int tid  = threadIdx.x;
    int wid  = tid >> 6;
    int lane = tid & 63;
    int l15  = lane & 15;
    int l4   = lane >> 4;
    size_t row0 = (size_t)blockIdx.x * GBM + wid * 32;

    f32x4 acc[2][8];
    #pragma unroll
    for (int tr = 0; tr < 2; ++tr)
        #pragma unroll
        for (int n = 0; n < 8; ++n) acc[tr][n] = (f32x4)(0.f);

    const float* Ar0 = A + (row0 + l15) * DF;
    const float* Ar1 = A + (row0 + 16 + l15) * DF;
    bool ok0 = (row0 + l15) < (size_t)M;
    bool ok1 = (row0 + 16 + l15) < (size_t)M;
    float4 zero = make_float4(0.f, 0.f, 0.f, 0.f);

    #pragma unroll
    for (int s = 0; s < 4; ++s) {
        int c0 = s * 32 + l4 * 4;
        float4 a00 = ok0 ? *(const float4*)&Ar0[c0]      : zero;
        float4 a01 = ok0 ? *(const float4*)&Ar0[c0 + 16] : zero;
        float4 a10 = ok1 ? *(const float4*)&Ar1[c0]      : zero;
        float4 a11 = ok1 ? *(const float4*)&Ar1[c0 + 16] : zero;
        if (relu) {
            a00 = f4_relu(a00); a01 = f4_relu(a01);
            a10 = f4_relu(a10); a11 = f4_relu(a11);
        }
        bf16x8 ah0, al0, ah1, al1;
        split8(a00, a01, ah0, al0);
        split8(a10, a11, ah1, al1);
        #pragma unroll
        for (int n = 0; n < 8; ++n) {
            size_t g = (size_t)((s * 8 + n) * 64 + lane) * 8;
            bf16x8 bh = *(const bf16x8*)&WHg[g];
            bf16x8 bl = *(const bf16x8*)&WLg[g];
            acc[0][n] = __builtin_amdgcn_mfma_f32_16x16x32_bf16(ah0, bh, acc[0][n], 0, 0, 0);
            acc[0][n] = __builtin_amdgcn_mfma_f32_16x16x32_bf16(ah0, bl, acc[0][n], 0, 0, 0);
            acc[0][n] = __builtin_amdgcn_mfma_f32_16x16x32_bf16(al0, bh, acc[0][n], 0, 0, 0);
            acc[1][n] = __builtin_amdgcn_mfma_f32_16x16x32_bf16(ah1, bh, acc[1][n], 0, 0, 0);
            acc[1][n] = __builtin_amdgcn_mfma_f32_16x16x32_bf16(ah1, bl, acc[1][n], 0, 0, 0);
            acc[1][n] = __builtin_amdgcn_mfma_f32_16x16x32_bf16(al1, bh, acc[1][n], 0, 0, 0);
        }
    }

    // C/D layout: col = n*16 + (lane&15), row = tr*16 + (lane>>4)*4 + q
    #pragma unroll
    for (int tr = 0; tr < 2; ++tr) {
        size_t rbase = row0 + tr * 16 + l4 * 4;
        #pragma unroll
        for (int q = 0; q < 4; ++q) {
            size_t r = rbase + q;
            if (r < (size_t)M) {
                #pragma unroll
                for (int n = 0; n < 8; ++n)
                    C[r * DF + n * 16 + l15] = acc[tr][n][q];
            }
        }
    }
}

// ---------- aggregation: out[i] = sum_{e into i} h[src]*norm + h[i]*dis[i]^2 + b ----------
// 4-wide unrolled edge loop for memory-level parallelism.
// FINAL=1: fuse relu + (.)@Wf + bf, write scalar per node to out.
template <int FINAL>
__global__ __launch_bounds__(256) void agg_kernel(const float* __restrict__ h,
                                                  const int2* __restrict__ edges,
                                                  const int* __restrict__ row_start,
                                                  const float* __restrict__ dis,
                                                  const float* __restrict__ bias,
                                                  const float* __restrict__ Wf,
                                                  const float* __restrict__ bf,
                                                  float* __restrict__ out, int N) {
    int gid = blockIdx.x * 8 + (threadIdx.x >> 5);   // node
    int l4  = threadIdx.x & 31;                      // float4 slot (32 x 4 = 128 feats)
    if (gid >= N) return;
    const float4* h4 = (const float4*)h;
    float d  = dis[gid];
    float sn = d * d;                                // self-loop norm
    float4 acc = h4[(size_t)gid * 32 + l4];
    float4 bv  = ((const float4*)bias)[l4];
    acc.x = acc.x * sn + bv.x;
    acc.y = acc.y * sn + bv.y;
    acc.z = acc.z * sn + bv.z;
    acc.w = acc.w * sn + bv.w;
    int s = row_start[gid], e = row_start[gid + 1];
    int p = s;
    for (; p + 4 <= e; p += 4) {
        int2 e0 = edges[p];
        int2 e1 = edges[p + 1];
        int2 e2 = edges[p + 2];
        int2 e3 = edges[p + 3];
        float4 v0 = h4[(size_t)e0.x * 32 + l4];
        float4 v1 = h4[(size_t)e1.x * 32 + l4];
        float4 v2 = h4[(size_t)e2.x * 32 + l4];
        float4 v3 = h4[(size_t)e3.x * 32 + l4];
        acc = f4_fma(v0, __int_as_float(e0.y), acc);
        acc = f4_fma(v1, __int_as_float(e1.y), acc);
        acc = f4_fma(v2, __int_as_float(e2.y), acc);
        acc = f4_fma(v3, __int_as_float(e3.y), acc);
    }
    for (; p < e; ++p) {
        int2 ed = edges[p];
        float4 v = h4[(size_t)ed.x * 32 + l4];
        acc = f4_fma(v, __int_as_float(ed.y), acc);
    }
    if (FINAL) {
        acc = f4_relu(acc);
        float4 w = ((const float4*)Wf)[l4];
        float pr = acc.x * w.x + acc.y * w.y + acc.z * w.z + acc.w * w.w;
        #pragma unroll
        for (int off = 16; off > 0; off >>= 1) pr += __shfl_xor(pr, off, 32);
        if (l4 == 0) out[gid] = pr + bf[0];
    } else {
        ((float4*)out)[(size_t)gid * 32 + l4] = acc;
    }
}

extern "C" void kernel_launch(void* const* d_in, const int* in_sizes, int n_in,
                              void* d_out, int out_size, void* d_ws, size_t ws_size,
                              hipStream_t stream) {
    const float* x  = (const float*)d_in[0];
    const int*   ei = (const int*)d_in[1];
    const float* Ws = (const float*)d_in[2];
    const float* bs = (const float*)d_in[3];
    const float* Wf = (const float*)d_in[4];
    const float* bf = (const float*)d_in[5];
    float* out = (float*)d_out;

    int N = in_sizes[0] / DF;
    int E = in_sizes[1] / 2;
    int L = in_sizes[2] / (DF * DF);

    char* p = (char*)d_ws;
    auto alloc = [&](size_t bytes) {
        char* r = p;
        p += (bytes + 255) & ~(size_t)255;
        return r;
    };
    int*   counts    = (int*)alloc((size_t)N * 4);
    int*   row_start = (int*)alloc((size_t)(N + 1) * 4);
    int*   cursor    = (int*)alloc((size_t)N * 4);
    float* dis       = (float*)alloc((size_t)N * 4);
    int2*  edges     = (int2*)alloc((size_t)E * 8);
    float* bufA      = (float*)alloc((size_t)N * DF * 4);
    float* bufB      = (float*)alloc((size_t)N * DF * 4);
    int*   partials  = (int*)alloc(1024 * 4);
    unsigned short* WHg = (unsigned short*)alloc((size_t)L * 2048 * 8 * 2);
    unsigned short* WLg = (unsigned short*)alloc((size_t)L * 2048 * 8 * 2);

    int NB = (N + 1023) / 1024;
    int WT = L * 2048;

    hipMemsetAsync(counts, 0, (size_t)N * 4, stream);
    wprep_kernel<<<(WT + 255) / 256, 256, 0, stream>>>(Ws, WHg, WLg, WT);
    count_kernel<<<(E + 255) / 256, 256, 0, stream>>>(ei, E, counts);
    scan_partials_kernel<<<NB, 1024, 0, stream>>>(counts, N, partials);
    scan_offsets_kernel<<<1, 1024, 0, stream>>>(partials, NB, &row_start[N]);
    scan_write_kernel<<<NB, 1024, 0, stream>>>(counts, N, partials, row_start, cursor, dis);
    scatter_kernel<<<(E + 255) / 256, 256, 0, stream>>>(ei, E, dis, cursor, edges);

    const float* hin = x;
    for (int l = 0; l < L; ++l) {
        gemm_mfma<<<(N + GBM - 1) / GBM, 256, 0, stream>>>(
            hin, WHg + (size_t)l * 16384, WLg + (size_t)l * 16384, bufA, N, l > 0);
        if (l == L - 1) {
            agg_kernel<1><<<(N + 7) / 8, 256, 0, stream>>>(bufA, edges, row_start, dis,
                                                           bs + (size_t)l * DF, Wf, bf, out, N);
        } else {
            agg_kernel<0><<<(N + 7) / 8, 256, 0, stream>>>(bufA, edges, row_start, dis,
                                                           bs + (size_t)l * DF, nullptr, nullptr,
                                                           bufB, N);
            hin = bufB;
        }
    }
}

// Round 4
// 591.024 us; speedup vs baseline: 1.2645x; 1.2645x over previous
//
#include <hip/hip_runtime.h>

#define DF 128  // feature dim (D_IN == H == 128)

typedef short bf16x8 __attribute__((ext_vector_type(8)));
typedef float f32x4 __attribute__((ext_vector_type(4)));
typedef _Float16 h16x4 __attribute__((ext_vector_type(4)));

// ---------- helpers ----------
__device__ __forceinline__ float4 f4_relu(float4 v) {
    v.x = fmaxf(v.x, 0.f); v.y = fmaxf(v.y, 0.f); v.z = fmaxf(v.z, 0.f); v.w = fmaxf(v.w, 0.f);
    return v;
}
__device__ __forceinline__ float4 f4_fma_h(h16x4 a, float s, float4 acc) {
    acc.x += (float)a[0] * s; acc.y += (float)a[1] * s;
    acc.z += (float)a[2] * s; acc.w += (float)a[3] * s;
    return acc;
}
__device__ __forceinline__ unsigned short f32_to_bf16_rne(float f) {
    unsigned u = __float_as_uint(f);
    unsigned r = (u + 0x7fffu + ((u >> 16) & 1u)) >> 16;
    return (unsigned short)r;
}
__device__ __forceinline__ float bf16_to_f32(unsigned short h) {
    return __uint_as_float(((unsigned)h) << 16);
}
// split 8 floats into hi/lo bf16 fragments
__device__ __forceinline__ void split8(float4 a, float4 b, bf16x8& hi, bf16x8& lo) {
    float v[8] = {a.x, a.y, a.z, a.w, b.x, b.y, b.z, b.w};
    #pragma unroll
    for (int j = 0; j < 8; ++j) {
        unsigned short h = f32_to_bf16_rne(v[j]);
        hi[j] = (short)h;
        float rem = v[j] - bf16_to_f32(h);
        lo[j] = (short)f32_to_bf16_rne(rem);
    }
}

// ---------- CSR build ----------
__global__ __launch_bounds__(256) void count_kernel(const int* __restrict__ ei, int E,
                                                    int* __restrict__ counts) {
    int e = blockIdx.x * 256 + threadIdx.x;
    if (e < E) atomicAdd(&counts[ei[E + e]], 1);
}

__global__ __launch_bounds__(1024) void scan_partials_kernel(const int* __restrict__ counts, int N,
                                                             int* __restrict__ partials) {
    __shared__ int wsum[16];
    int t = threadIdx.x, lane = t & 63, wid = t >> 6;
    int i = blockIdx.x * 1024 + t;
    int c = (i < N) ? counts[i] : 0;
    #pragma unroll
    for (int off = 32; off > 0; off >>= 1) c += __shfl_xor(c, off, 64);
    if (lane == 0) wsum[wid] = c;
    __syncthreads();
    if (t == 0) {
        int s = 0;
        #pragma unroll
        for (int w = 0; w < 16; ++w) s += wsum[w];
        partials[blockIdx.x] = s;
    }
}

__global__ __launch_bounds__(1024) void scan_offsets_kernel(int* __restrict__ partials, int NB,
                                                            int* __restrict__ row_end) {
    __shared__ int wtot[16];
    int t = threadIdx.x, lane = t & 63, wid = t >> 6;
    int c = (t < NB) ? partials[t] : 0;
    int incl = c;
    #pragma unroll
    for (int off = 1; off < 64; off <<= 1) {
        int n = __shfl_up(incl, off, 64);
        if (lane >= off) incl += n;
    }
    if (lane == 63) wtot[wid] = incl;
    __syncthreads();
    int wbase = 0, total = 0;
    #pragma unroll
    for (int w = 0; w < 16; ++w) {
        int v = wtot[w];
        if (w < wid) wbase += v;
        total += v;
    }
    if (t < NB) partials[t] = wbase + incl - c;
    if (t == 0) *row_end = total;
}

__global__ __launch_bounds__(1024) void scan_write_kernel(const int* __restrict__ counts, int N,
                                                          const int* __restrict__ partials,
                                                          int* __restrict__ row_start,
                                                          int* __restrict__ cursor,
                                                          float* __restrict__ dis) {
    __shared__ int wtot[16];
    int t = threadIdx.x, lane = t & 63, wid = t >> 6;
    int i = blockIdx.x * 1024 + t;
    int c = (i < N) ? counts[i] : 0;
    int incl = c;
    #pragma unroll
    for (int off = 1; off < 64; off <<= 1) {
        int n = __shfl_up(incl, off, 64);
        if (lane >= off) incl += n;
    }
    if (lane == 63) wtot[wid] = incl;
    __syncthreads();
    int wbase = 0;
    #pragma unroll
    for (int w = 0; w < 16; ++w) {
        int v = wtot[w];
        if (w < wid) wbase += v;
    }
    if (i < N) {
        int excl = partials[blockIdx.x] + wbase + incl - c;
        row_start[i] = excl;
        cursor[i]    = excl;
        dis[i]       = rsqrtf((float)(c + 1));   // +1 self loop
    }
}

__global__ __launch_bounds__(256) void scatter_kernel(const int* __restrict__ ei, int E,
                                                      const float* __restrict__ dis,
                                                      int* __restrict__ cursor,
                                                      int2* __restrict__ edges) {
    int e = blockIdx.x * 256 + threadIdx.x;
    if (e < E) {
        int s = ei[e];
        int d = ei[E + e];
        int pos = atomicAdd(&cursor[d], 1);
        int2 packed;
        packed.x = s;
        packed.y = __float_as_int(dis[s] * dis[d]);
        edges[pos] = packed;
    }
}

// ---------- W fragment prep: Ws[L][128][128] -> hi/lo bf16 fragment planes ----------
__global__ __launch_bounds__(256) void wprep_kernel(const float* __restrict__ Ws,
                                                    unsigned short* __restrict__ WHg,
                                                    unsigned short* __restrict__ WLg,
                                                    int total) {
    int g = blockIdx.x * 256 + threadIdx.x;
    if (g >= total) return;
    int l = g >> 11;         // layer
    int t = g & 2047;
    int s = t >> 9;
    int n = (t >> 6) & 7;
    int lane = t & 63;
    int kb = s * 32 + ((lane >> 4) << 2);
    int c  = n * 16 + (lane & 15);
    const float* W = Ws + (size_t)l * DF * DF;
    bf16x8 hi, lo;
    #pragma unroll
    for (int j = 0; j < 8; ++j) {
        int k = kb + (j & 3) + ((j >> 2) << 4);
        float w = W[k * DF + c];
        unsigned short h = f32_to_bf16_rne(w);
        hi[j] = (short)h;
        lo[j] = (short)f32_to_bf16_rne(w - bf16_to_f32(h));
    }
    *(bf16x8*)&WHg[(size_t)g * 8] = hi;
    *(bf16x8*)&WLg[(size_t)g * 8] = lo;
}

// ---------- MFMA split-bf16 GEMM: C_fp16[M,128] = (relu?relu(A):A) @ W ----------
#define GBM 128
__global__ __launch_bounds__(256) void gemm_mfma(const float* __restrict__ A,
                                                 const unsigned short* __restrict__ WHg,
                                                 const unsigned short* __restrict__ WLg,
                                                 _Float16* __restrict__ C,
                                                 int M, int relu) {
    int tid  = threadIdx.x;
    int wid  = tid >> 6;
    int lane = tid & 63;
    int l15  = lane & 15;
    int l4   = lane >> 4;
    size_t row0 = (size_t)blockIdx.x * GBM + wid * 32;

    f32x4 acc[2][8];
    #pragma unroll
    for (int tr = 0; tr < 2; ++tr)
        #pragma unroll
        for (int n = 0; n < 8; ++n) acc[tr][n] = (f32x4)(0.f);

    const float* Ar0 = A + (row0 + l15) * DF;
    const float* Ar1 = A + (row0 + 16 + l15) * DF;
    bool ok0 = (row0 + l15) < (size_t)M;
    bool ok1 = (row0 + 16 + l15) < (size_t)M;
    float4 zero = make_float4(0.f, 0.f, 0.f, 0.f);

    #pragma unroll
    for (int s = 0; s < 4; ++s) {
        int c0 = s * 32 + l4 * 4;
        float4 a00 = ok0 ? *(const float4*)&Ar0[c0]      : zero;
        float4 a01 = ok0 ? *(const float4*)&Ar0[c0 + 16] : zero;
        float4 a10 = ok1 ? *(const float4*)&Ar1[c0]      : zero;
        float4 a11 = ok1 ? *(const float4*)&Ar1[c0 + 16] : zero;
        if (relu) {
            a00 = f4_relu(a00); a01 = f4_relu(a01);
            a10 = f4_relu(a10); a11 = f4_relu(a11);
        }
        bf16x8 ah0, al0, ah1, al1;
        split8(a00, a01, ah0, al0);
        split8(a10, a11, ah1, al1);
        #pragma unroll
        for (int n = 0; n < 8; ++n) {
            size_t g = (size_t)((s * 8 + n) * 64 + lane) * 8;
            bf16x8 bh = *(const bf16x8*)&WHg[g];
            bf16x8 bl = *(const bf16x8*)&WLg[g];
            acc[0][n] = __builtin_amdgcn_mfma_f32_16x16x32_bf16(ah0, bh, acc[0][n], 0, 0, 0);
            acc[0][n] = __builtin_amdgcn_mfma_f32_16x16x32_bf16(ah0, bl, acc[0][n], 0, 0, 0);
            acc[0][n] = __builtin_amdgcn_mfma_f32_16x16x32_bf16(al0, bh, acc[0][n], 0, 0, 0);
            acc[1][n] = __builtin_amdgcn_mfma_f32_16x16x32_bf16(ah1, bh, acc[1][n], 0, 0, 0);
            acc[1][n] = __builtin_amdgcn_mfma_f32_16x16x32_bf16(ah1, bl, acc[1][n], 0, 0, 0);
            acc[1][n] = __builtin_amdgcn_mfma_f32_16x16x32_bf16(al1, bh, acc[1][n], 0, 0, 0);
        }
    }

    // C/D layout: col = n*16 + (lane&15), row = tr*16 + (lane>>4)*4 + q
    #pragma unroll
    for (int tr = 0; tr < 2; ++tr) {
        size_t rbase = row0 + tr * 16 + l4 * 4;
        #pragma unroll
        for (int q = 0; q < 4; ++q) {
            size_t r = rbase + q;
            if (r < (size_t)M) {
                #pragma unroll
                for (int n = 0; n < 8; ++n)
                    C[r * DF + n * 16 + l15] = (_Float16)acc[tr][n][q];
            }
        }
    }
}

// ---------- aggregation: out[i] = sum_{e into i} h16[src]*norm + h16[i]*dis^2 + b ----------
// h is fp16 (256 B rows): halves gather bytes, h fits aggregate L2 (25.6 < 32 MB).
// FINAL=1: fuse relu + (.)@Wf + bf, write scalar per node.
template <int FINAL>
__global__ __launch_bounds__(256) void agg_kernel(const _Float16* __restrict__ h,
                                                  const int2* __restrict__ edges,
                                                  const int* __restrict__ row_start,
                                                  const float* __restrict__ dis,
                                                  const float* __restrict__ bias,
                                                  const float* __restrict__ Wf,
                                                  const float* __restrict__ bf,
                                                  float* __restrict__ out, int N) {
    int gid = blockIdx.x * 8 + (threadIdx.x >> 5);   // node
    int l4  = threadIdx.x & 31;                      // 4-feature slot
    if (gid >= N) return;
    const h16x4* hv = (const h16x4*)h;               // 32 per row
    float d  = dis[gid];
    float sn = d * d;                                // self-loop norm
    float4 bv = ((const float4*)bias)[l4];
    float4 acc = make_float4(bv.x, bv.y, bv.z, bv.w);
    acc = f4_fma_h(hv[(size_t)gid * 32 + l4], sn, acc);
    int s = row_start[gid], e = row_start[gid + 1];
    int p = s;
    for (; p + 4 <= e; p += 4) {
        int2 e0 = edges[p];
        int2 e1 = edges[p + 1];
        int2 e2 = edges[p + 2];
        int2 e3 = edges[p + 3];
        h16x4 v0 = hv[(size_t)e0.x * 32 + l4];
        h16x4 v1 = hv[(size_t)e1.x * 32 + l4];
        h16x4 v2 = hv[(size_t)e2.x * 32 + l4];
        h16x4 v3 = hv[(size_t)e3.x * 32 + l4];
        acc = f4_fma_h(v0, __int_as_float(e0.y), acc);
        acc = f4_fma_h(v1, __int_as_float(e1.y), acc);
        acc = f4_fma_h(v2, __int_as_float(e2.y), acc);
        acc = f4_fma_h(v3, __int_as_float(e3.y), acc);
    }
    for (; p < e; ++p) {
        int2 ed = edges[p];
        acc = f4_fma_h(hv[(size_t)ed.x * 32 + l4], __int_as_float(ed.y), acc);
    }
    if (FINAL) {
        acc = f4_relu(acc);
        float4 w = ((const float4*)Wf)[l4];
        float pr = acc.x * w.x + acc.y * w.y + acc.z * w.z + acc.w * w.w;
        #pragma unroll
        for (int off = 16; off > 0; off >>= 1) pr += __shfl_xor(pr, off, 32);
        if (l4 == 0) out[gid] = pr + bf[0];
    } else {
        ((float4*)out)[(size_t)gid * 32 + l4] = acc;
    }
}

extern "C" void kernel_launch(void* const* d_in, const int* in_sizes, int n_in,
                              void* d_out, int out_size, void* d_ws, size_t ws_size,
                              hipStream_t stream) {
    const float* x  = (const float*)d_in[0];
    const int*   ei = (const int*)d_in[1];
    const float* Ws = (const float*)d_in[2];
    const float* bs = (const float*)d_in[3];
    const float* Wf = (const float*)d_in[4];
    const float* bf = (const float*)d_in[5];
    float* out = (float*)d_out;

    int N = in_sizes[0] / DF;
    int E = in_sizes[1] / 2;
    int L = in_sizes[2] / (DF * DF);

    char* p = (char*)d_ws;
    auto alloc = [&](size_t bytes) {
        char* r = p;
        p += (bytes + 255) & ~(size_t)255;
        return r;
    };
    int*   counts    = (int*)alloc((size_t)N * 4);
    int*   row_start = (int*)alloc((size_t)(N + 1) * 4);
    int*   cursor    = (int*)alloc((size_t)N * 4);
    float* dis       = (float*)alloc((size_t)N * 4);
    int2*  edges     = (int2*)alloc((size_t)E * 8);
    _Float16* bufH   = (_Float16*)alloc((size_t)N * DF * 2);  // fp16 gemm output
    float* bufB      = (float*)alloc((size_t)N * DF * 4);     // fp32 agg output
    int*   partials  = (int*)alloc(1024 * 4);
    unsigned short* WHg = (unsigned short*)alloc((size_t)L * 2048 * 8 * 2);
    unsigned short* WLg = (unsigned short*)alloc((size_t)L * 2048 * 8 * 2);

    int NB = (N + 1023) / 1024;
    int WT = L * 2048;

    hipMemsetAsync(counts, 0, (size_t)N * 4, stream);
    wprep_kernel<<<(WT + 255) / 256, 256, 0, stream>>>(Ws, WHg, WLg, WT);
    count_kernel<<<(E + 255) / 256, 256, 0, stream>>>(ei, E, counts);
    scan_partials_kernel<<<NB, 1024, 0, stream>>>(counts, N, partials);
    scan_offsets_kernel<<<1, 1024, 0, stream>>>(partials, NB, &row_start[N]);
    scan_write_kernel<<<NB, 1024, 0, stream>>>(counts, N, partials, row_start, cursor, dis);
    scatter_kernel<<<(E + 255) / 256, 256, 0, stream>>>(ei, E, dis, cursor, edges);

    const float* hin = x;
    for (int l = 0; l < L; ++l) {
        gemm_mfma<<<(N + GBM - 1) / GBM, 256, 0, stream>>>(
            hin, WHg + (size_t)l * 16384, WLg + (size_t)l * 16384, bufH, N, l > 0);
        if (l == L - 1) {
            agg_kernel<1><<<(N + 7) / 8, 256, 0, stream>>>(bufH, edges, row_start, dis,
                                                           bs + (size_t)l * DF, Wf, bf, out, N);
        } else {
            agg_kernel<0><<<(N + 7) / 8, 256, 0, stream>>>(bufH, edges, row_start, dis,
                                                           bs + (size_t)l * DF, nullptr, nullptr,
                                                           bufB, N);
            hin = bufB;
        }
    }
}

// Round 5
// 523.874 us; speedup vs baseline: 1.4266x; 1.1282x over previous
//
#include <hip/hip_runtime.h>

#define DF 128  // feature dim (D_IN == H == 128)

typedef short bf16x8 __attribute__((ext_vector_type(8)));
typedef float f32x4 __attribute__((ext_vector_type(4)));
typedef _Float16 h16x8 __attribute__((ext_vector_type(8)));

// ---------- helpers ----------
__device__ __forceinline__ float4 f4_relu(float4 v) {
    v.x = fmaxf(v.x, 0.f); v.y = fmaxf(v.y, 0.f); v.z = fmaxf(v.z, 0.f); v.w = fmaxf(v.w, 0.f);
    return v;
}
__device__ __forceinline__ unsigned short f32_to_bf16_rne(float f) {
    unsigned u = __float_as_uint(f);
    unsigned r = (u + 0x7fffu + ((u >> 16) & 1u)) >> 16;
    return (unsigned short)r;
}
__device__ __forceinline__ float bf16_to_f32(unsigned short h) {
    return __uint_as_float(((unsigned)h) << 16);
}
// split 8 floats into hi/lo bf16 fragments
__device__ __forceinline__ void split8(float4 a, float4 b, bf16x8& hi, bf16x8& lo) {
    float v[8] = {a.x, a.y, a.z, a.w, b.x, b.y, b.z, b.w};
    #pragma unroll
    for (int j = 0; j < 8; ++j) {
        unsigned short h = f32_to_bf16_rne(v[j]);
        hi[j] = (short)h;
        float rem = v[j] - bf16_to_f32(h);
        lo[j] = (short)f32_to_bf16_rne(rem);
    }
}

// ---------- CSR build ----------
// count + rank: rank[e] = position of edge e within its dst's list
__global__ __launch_bounds__(256) void count_kernel(const int* __restrict__ ei, int E,
                                                    int* __restrict__ counts,
                                                    int* __restrict__ rank) {
    int e = blockIdx.x * 256 + threadIdx.x;
    if (e < E) rank[e] = atomicAdd(&counts[ei[E + e]], 1);
}

__global__ __launch_bounds__(1024) void scan_partials_kernel(const int* __restrict__ counts, int N,
                                                             int* __restrict__ partials) {
    __shared__ int wsum[16];
    int t = threadIdx.x, lane = t & 63, wid = t >> 6;
    int i = blockIdx.x * 1024 + t;
    int c = (i < N) ? counts[i] : 0;
    #pragma unroll
    for (int off = 32; off > 0; off >>= 1) c += __shfl_xor(c, off, 64);
    if (lane == 0) wsum[wid] = c;
    __syncthreads();
    if (t == 0) {
        int s = 0;
        #pragma unroll
        for (int w = 0; w < 16; ++w) s += wsum[w];
        partials[blockIdx.x] = s;
    }
}

__global__ __launch_bounds__(1024) void scan_offsets_kernel(int* __restrict__ partials, int NB,
                                                            int* __restrict__ row_end) {
    __shared__ int wtot[16];
    int t = threadIdx.x, lane = t & 63, wid = t >> 6;
    int c = (t < NB) ? partials[t] : 0;
    int incl = c;
    #pragma unroll
    for (int off = 1; off < 64; off <<= 1) {
        int n = __shfl_up(incl, off, 64);
        if (lane >= off) incl += n;
    }
    if (lane == 63) wtot[wid] = incl;
    __syncthreads();
    int wbase = 0, total = 0;
    #pragma unroll
    for (int w = 0; w < 16; ++w) {
        int v = wtot[w];
        if (w < wid) wbase += v;
        total += v;
    }
    if (t < NB) partials[t] = wbase + incl - c;
    if (t == 0) *row_end = total;
}

__global__ __launch_bounds__(1024) void scan_write_kernel(const int* __restrict__ counts, int N,
                                                          const int* __restrict__ partials,
                                                          int* __restrict__ row_start,
                                                          float* __restrict__ dis) {
    __shared__ int wtot[16];
    int t = threadIdx.x, lane = t & 63, wid = t >> 6;
    int i = blockIdx.x * 1024 + t;
    int c = (i < N) ? counts[i] : 0;
    int incl = c;
    #pragma unroll
    for (int off = 1; off < 64; off <<= 1) {
        int n = __shfl_up(incl, off, 64);
        if (lane >= off) incl += n;
    }
    if (lane == 63) wtot[wid] = incl;
    __syncthreads();
    int wbase = 0;
    #pragma unroll
    for (int w = 0; w < 16; ++w) {
        int v = wtot[w];
        if (w < wid) wbase += v;
    }
    if (i < N) {
        int excl = partials[blockIdx.x] + wbase + incl - c;
        row_start[i] = excl;
        dis[i]       = rsqrtf((float)(c + 1));   // +1 self loop
    }
}

// place: pos = row_start[dst] + rank[e]; record = src only (4B)
__global__ __launch_bounds__(256) void place_kernel(const int* __restrict__ ei, int E,
                                                    const int* __restrict__ rank,
                                                    const int* __restrict__ row_start,
                                                    int* __restrict__ edges4) {
    int e = blockIdx.x * 256 + threadIdx.x;
    if (e < E) {
        int d = ei[E + e];
        edges4[row_start[d] + rank[e]] = ei[e];
    }
}

// ---------- W fragment prep: Ws[L][128][128] -> hi/lo bf16 fragment planes ----------
__global__ __launch_bounds__(256) void wprep_kernel(const float* __restrict__ Ws,
                                                    unsigned short* __restrict__ WHg,
                                                    unsigned short* __restrict__ WLg,
                                                    int total) {
    int g = blockIdx.x * 256 + threadIdx.x;
    if (g >= total) return;
    int l = g >> 11;         // layer
    int t = g & 2047;
    int s = t >> 9;
    int n = (t >> 6) & 7;
    int lane = t & 63;
    int kb = s * 32 + ((lane >> 4) << 2);
    int c  = n * 16 + (lane & 15);
    const float* W = Ws + (size_t)l * DF * DF;
    bf16x8 hi, lo;
    #pragma unroll
    for (int j = 0; j < 8; ++j) {
        int k = kb + (j & 3) + ((j >> 2) << 4);
        float w = W[k * DF + c];
        unsigned short h = f32_to_bf16_rne(w);
        hi[j] = (short)h;
        lo[j] = (short)f32_to_bf16_rne(w - bf16_to_f32(h));
    }
    *(bf16x8*)&WHg[(size_t)g * 8] = hi;
    *(bf16x8*)&WLg[(size_t)g * 8] = lo;
}

// ---------- MFMA split-bf16 GEMM with pre-scale epilogue ----------
// C_fp16[r][c] = ((relu?relu(A):A) @ W)[r][c] * dis[r]   (g = h*dis)
#define GBM 128
__global__ __launch_bounds__(256) void gemm_mfma(const float* __restrict__ A,
                                                 const unsigned short* __restrict__ WHg,
                                                 const unsigned short* __restrict__ WLg,
                                                 const float* __restrict__ dis,
                                                 _Float16* __restrict__ C,
                                                 int M, int relu) {
    int tid  = threadIdx.x;
    int wid  = tid >> 6;
    int lane = tid & 63;
    int l15  = lane & 15;
    int l4   = lane >> 4;
    size_t row0 = (size_t)blockIdx.x * GBM + wid * 32;

    f32x4 acc[2][8];
    #pragma unroll
    for (int tr = 0; tr < 2; ++tr)
        #pragma unroll
        for (int n = 0; n < 8; ++n) acc[tr][n] = (f32x4)(0.f);

    const float* Ar0 = A + (row0 + l15) * DF;
    const float* Ar1 = A + (row0 + 16 + l15) * DF;
    bool ok0 = (row0 + l15) < (size_t)M;
    bool ok1 = (row0 + 16 + l15) < (size_t)M;
    float4 zero = make_float4(0.f, 0.f, 0.f, 0.f);

    #pragma unroll
    for (int s = 0; s < 4; ++s) {
        int c0 = s * 32 + l4 * 4;
        float4 a00 = ok0 ? *(const float4*)&Ar0[c0]      : zero;
        float4 a01 = ok0 ? *(const float4*)&Ar0[c0 + 16] : zero;
        float4 a10 = ok1 ? *(const float4*)&Ar1[c0]      : zero;
        float4 a11 = ok1 ? *(const float4*)&Ar1[c0 + 16] : zero;
        if (relu) {
            a00 = f4_relu(a00); a01 = f4_relu(a01);
            a10 = f4_relu(a10); a11 = f4_relu(a11);
        }
        bf16x8 ah0, al0, ah1, al1;
        split8(a00, a01, ah0, al0);
        split8(a10, a11, ah1, al1);
        #pragma unroll
        for (int n = 0; n < 8; ++n) {
            size_t g = (size_t)((s * 8 + n) * 64 + lane) * 8;
            bf16x8 bh = *(const bf16x8*)&WHg[g];
            bf16x8 bl = *(const bf16x8*)&WLg[g];
            acc[0][n] = __builtin_amdgcn_mfma_f32_16x16x32_bf16(ah0, bh, acc[0][n], 0, 0, 0);
            acc[0][n] = __builtin_amdgcn_mfma_f32_16x16x32_bf16(ah0, bl, acc[0][n], 0, 0, 0);
            acc[0][n] = __builtin_amdgcn_mfma_f32_16x16x32_bf16(al0, bh, acc[0][n], 0, 0, 0);
            acc[1][n] = __builtin_amdgcn_mfma_f32_16x16x32_bf16(ah1, bh, acc[1][n], 0, 0, 0);
            acc[1][n] = __builtin_amdgcn_mfma_f32_16x16x32_bf16(ah1, bl, acc[1][n], 0, 0, 0);
            acc[1][n] = __builtin_amdgcn_mfma_f32_16x16x32_bf16(al1, bh, acc[1][n], 0, 0, 0);
        }
    }

    // C/D layout: col = n*16 + (lane&15), row = tr*16 + (lane>>4)*4 + q
    #pragma unroll
    for (int tr = 0; tr < 2; ++tr) {
        size_t rbase = row0 + tr * 16 + l4 * 4;
        #pragma unroll
        for (int q = 0; q < 4; ++q) {
            size_t r = rbase + q;
            if (r < (size_t)M) {
                float ds = dis[r];
                #pragma unroll
                for (int n = 0; n < 8; ++n)
                    C[r * DF + n * 16 + l15] = (_Float16)(acc[tr][n][q] * ds);
            }
        }
    }
}

// ---------- aggregation: out[i] = dis[i]*(g[i] + sum_e g[src_e]) + b ----------
// g fp16 rows (256 B); 16 lanes/node, 16 B loads; pure-add inner loop.
// FINAL=1: fuse relu + (.)@Wf + bf, write scalar per node.
template <int FINAL>
__global__ __launch_bounds__(256) void agg_kernel(const _Float16* __restrict__ g,
                                                  const int* __restrict__ edges4,
                                                  const int* __restrict__ row_start,
                                                  const float* __restrict__ dis,
                                                  const float* __restrict__ bias,
                                                  const float* __restrict__ Wf,
                                                  const float* __restrict__ bf,
                                                  float* __restrict__ out, int N) {
    int gid = blockIdx.x * 16 + (threadIdx.x >> 4);  // node
    int l8  = threadIdx.x & 15;                      // 8-feature slot
    if (gid >= N) return;
    const h16x8* gv = (const h16x8*)g;               // 16 per row
    float acc[8];
    {
        h16x8 self = gv[(size_t)gid * 16 + l8];
        #pragma unroll
        for (int j = 0; j < 8; ++j) acc[j] = (float)self[j];
    }
    int s = row_start[gid], e = row_start[gid + 1];
    int p = s;
    for (; p + 4 <= e; p += 4) {
        int s0 = edges4[p];
        int s1 = edges4[p + 1];
        int s2 = edges4[p + 2];
        int s3 = edges4[p + 3];
        h16x8 v0 = gv[(size_t)s0 * 16 + l8];
        h16x8 v1 = gv[(size_t)s1 * 16 + l8];
        h16x8 v2 = gv[(size_t)s2 * 16 + l8];
        h16x8 v3 = gv[(size_t)s3 * 16 + l8];
        #pragma unroll
        for (int j = 0; j < 8; ++j)
            acc[j] += (float)v0[j] + (float)v1[j] + (float)v2[j] + (float)v3[j];
    }
    for (; p < e; ++p) {
        h16x8 v = gv[(size_t)edges4[p] * 16 + l8];
        #pragma unroll
        for (int j = 0; j < 8; ++j) acc[j] += (float)v[j];
    }
    float d = dis[gid];
    if (FINAL) {
        float pr = 0.f;
        #pragma unroll
        for (int j = 0; j < 8; ++j) {
            float v = fmaxf(acc[j] * d + bias[l8 * 8 + j], 0.f);
            pr += v * Wf[l8 * 8 + j];
        }
        #pragma unroll
        for (int off = 8; off > 0; off >>= 1) pr += __shfl_xor(pr, off, 16);
        if (l8 == 0) out[gid] = pr + bf[0];
    } else {
        float4 o0, o1;
        o0.x = acc[0] * d + bias[l8 * 8 + 0];
        o0.y = acc[1] * d + bias[l8 * 8 + 1];
        o0.z = acc[2] * d + bias[l8 * 8 + 2];
        o0.w = acc[3] * d + bias[l8 * 8 + 3];
        o1.x = acc[4] * d + bias[l8 * 8 + 4];
        o1.y = acc[5] * d + bias[l8 * 8 + 5];
        o1.z = acc[6] * d + bias[l8 * 8 + 6];
        o1.w = acc[7] * d + bias[l8 * 8 + 7];
        float4* op = (float4*)&out[(size_t)gid * DF + l8 * 8];
        op[0] = o0;
        op[1] = o1;
    }
}

extern "C" void kernel_launch(void* const* d_in, const int* in_sizes, int n_in,
                              void* d_out, int out_size, void* d_ws, size_t ws_size,
                              hipStream_t stream) {
    const float* x  = (const float*)d_in[0];
    const int*   ei = (const int*)d_in[1];
    const float* Ws = (const float*)d_in[2];
    const float* bs = (const float*)d_in[3];
    const float* Wf = (const float*)d_in[4];
    const float* bf = (const float*)d_in[5];
    float* out = (float*)d_out;

    int N = in_sizes[0] / DF;
    int E = in_sizes[1] / 2;
    int L = in_sizes[2] / (DF * DF);

    char* p = (char*)d_ws;
    auto alloc = [&](size_t bytes) {
        char* r = p;
        p += (bytes + 255) & ~(size_t)255;
        return r;
    };
    int*   counts    = (int*)alloc((size_t)N * 4);
    int*   row_start = (int*)alloc((size_t)(N + 1) * 4);
    float* dis       = (float*)alloc((size_t)N * 4);
    int*   rank      = (int*)alloc((size_t)E * 4);
    int*   edges4    = (int*)alloc((size_t)E * 4);
    _Float16* bufG   = (_Float16*)alloc((size_t)N * DF * 2);  // g = h*dis, fp16
    float* bufB      = (float*)alloc((size_t)N * DF * 4);     // fp32 agg output
    int*   partials  = (int*)alloc(1024 * 4);
    unsigned short* WHg = (unsigned short*)alloc((size_t)L * 2048 * 8 * 2);
    unsigned short* WLg = (unsigned short*)alloc((size_t)L * 2048 * 8 * 2);

    int NB = (N + 1023) / 1024;
    int WT = L * 2048;

    hipMemsetAsync(counts, 0, (size_t)N * 4, stream);
    wprep_kernel<<<(WT + 255) / 256, 256, 0, stream>>>(Ws, WHg, WLg, WT);
    count_kernel<<<(E + 255) / 256, 256, 0, stream>>>(ei, E, counts, rank);
    scan_partials_kernel<<<NB, 1024, 0, stream>>>(counts, N, partials);
    scan_offsets_kernel<<<1, 1024, 0, stream>>>(partials, NB, &row_start[N]);
    scan_write_kernel<<<NB, 1024, 0, stream>>>(counts, N, partials, row_start, dis);
    place_kernel<<<(E + 255) / 256, 256, 0, stream>>>(ei, E, rank, row_start, edges4);

    const float* hin = x;
    for (int l = 0; l < L; ++l) {
        gemm_mfma<<<(N + GBM - 1) / GBM, 256, 0, stream>>>(
            hin, WHg + (size_t)l * 16384, WLg + (size_t)l * 16384, dis, bufG, N, l > 0);
        if (l == L - 1) {
            agg_kernel<1><<<(N + 15) / 16, 256, 0, stream>>>(bufG, edges4, row_start, dis,
                                                             bs + (size_t)l * DF, Wf, bf, out, N);
        } else {
            agg_kernel<0><<<(N + 15) / 16, 256, 0, stream>>>(bufG, edges4, row_start, dis,
                                                             bs + (size_t)l * DF, nullptr, nullptr,
                                                             bufB, N);
            hin = bufB;
        }
    }
}

// Round 6
// 472.403 us; speedup vs baseline: 1.5820x; 1.1090x over previous
//
#include <hip/hip_runtime.h>

#define DF 128   // feature dim (D_IN == H == 128)
#define EB 4096  // edges per radix block

typedef short bf16x8 __attribute__((ext_vector_type(8)));
typedef float f32x4 __attribute__((ext_vector_type(4)));
typedef _Float16 h16x8 __attribute__((ext_vector_type(8)));

// ---------- helpers ----------
__device__ __forceinline__ float4 f4_relu(float4 v) {
    v.x = fmaxf(v.x, 0.f); v.y = fmaxf(v.y, 0.f); v.z = fmaxf(v.z, 0.f); v.w = fmaxf(v.w, 0.f);
    return v;
}
__device__ __forceinline__ unsigned short f32_to_bf16_rne(float f) {
    unsigned u = __float_as_uint(f);
    unsigned r = (u + 0x7fffu + ((u >> 16) & 1u)) >> 16;
    return (unsigned short)r;
}
__device__ __forceinline__ float bf16_to_f32(unsigned short h) {
    return __uint_as_float(((unsigned)h) << 16);
}
__device__ __forceinline__ void split8(float4 a, float4 b, bf16x8& hi, bf16x8& lo) {
    float v[8] = {a.x, a.y, a.z, a.w, b.x, b.y, b.z, b.w};
    #pragma unroll
    for (int j = 0; j < 8; ++j) {
        unsigned short h = f32_to_bf16_rne(v[j]);
        hi[j] = (short)h;
        float rem = v[j] - bf16_to_f32(h);
        lo[j] = (short)f32_to_bf16_rne(rem);
    }
}

// ---------- radix CSR build (all atomics in LDS) ----------
// p1a: per-block histogram over buckets (dst>>8)
__global__ __launch_bounds__(256) void p1a_hist(const int* __restrict__ ei, int E,
                                                int NBUKP, int* __restrict__ parthist) {
    __shared__ int hist[512];
    int t = threadIdx.x;
    for (int i = t; i < NBUKP; i += 256) hist[i] = 0;
    __syncthreads();
    int e0 = blockIdx.x * EB;
    #pragma unroll
    for (int j = 0; j < EB / 256; ++j) {
        int e = e0 + j * 256 + t;
        if (e < E) atomicAdd(&hist[ei[E + e] >> 8], 1);
    }
    __syncthreads();
    for (int i = t; i < NBUKP; i += 256)
        parthist[(size_t)blockIdx.x * NBUKP + i] = hist[i];
}

// colscan: per bucket k, exclusive scan of parthist[b][k] over blocks b (in place);
// bucket total -> btotal[k]
__global__ __launch_bounds__(256) void colscan_kernel(int* __restrict__ parthist,
                                                      int NBLK, int NBUKP,
                                                      int* __restrict__ btotal) {
    __shared__ int wsum[4];
    int k = blockIdx.x;
    int t = threadIdx.x;
    int Q = (NBLK + 255) / 256;   // chunks per thread (<=8)
    int b0 = t * Q;
    int local[8];
    int s = 0;
    for (int j = 0; j < Q; ++j) {
        int b = b0 + j;
        int v = (b < NBLK) ? parthist[(size_t)b * NBUKP + k] : 0;
        local[j] = v;
        s += v;
    }
    int lane = t & 63, wid = t >> 6;
    int incl = s;
    #pragma unroll
    for (int off = 1; off < 64; off <<= 1) {
        int n = __shfl_up(incl, off, 64);
        if (lane >= off) incl += n;
    }
    if (lane == 63) wsum[wid] = incl;
    __syncthreads();
    int wbase = 0, total = 0;
    #pragma unroll
    for (int w = 0; w < 4; ++w) {
        int v = wsum[w];
        if (w < wid) wbase += v;
        total += v;
    }
    int run = wbase + incl - s;
    for (int j = 0; j < Q; ++j) {
        int b = b0 + j;
        if (b < NBLK) parthist[(size_t)b * NBUKP + k] = run;
        run += local[j];
    }
    if (t == 0) btotal[k] = total;
}

// 1-block exclusive scan (<=1024 entries), in place; total -> *scan_end
__global__ __launch_bounds__(1024) void scan_offsets_kernel(int* __restrict__ partials, int NB,
                                                            int* __restrict__ scan_end) {
    __shared__ int wtot[16];
    int t = threadIdx.x, lane = t & 63, wid = t >> 6;
    int c = (t < NB) ? partials[t] : 0;
    int incl = c;
    #pragma unroll
    for (int off = 1; off < 64; off <<= 1) {
        int n = __shfl_up(incl, off, 64);
        if (lane >= off) incl += n;
    }
    if (lane == 63) wtot[wid] = incl;
    __syncthreads();
    int wbase = 0, total = 0;
    #pragma unroll
    for (int w = 0; w < 16; ++w) {
        int v = wtot[w];
        if (w < wid) wbase += v;
        total += v;
    }
    if (t < NB) partials[t] = wbase + incl - c;
    if (t == 0) *scan_end = total;
}

// p1c: scatter packed records (src<<8 | dst&255) into bucket regions (LDS cursors)
__global__ __launch_bounds__(256) void p1c_scatter(const int* __restrict__ ei, int E,
                                                   int NBUK, int NBUKP,
                                                   const int* __restrict__ parthist,
                                                   const int* __restrict__ bbase,
                                                   unsigned int* __restrict__ pbuf) {
    __shared__ int cur[512];
    int t = threadIdx.x;
    for (int i = t; i < NBUK; i += 256)
        cur[i] = bbase[i] + parthist[(size_t)blockIdx.x * NBUKP + i];
    __syncthreads();
    int e0 = blockIdx.x * EB;
    #pragma unroll
    for (int j = 0; j < EB / 256; ++j) {
        int e = e0 + j * 256 + t;
        if (e < E) {
            int s = ei[e], d = ei[E + e];
            int pos = atomicAdd(&cur[d >> 8], 1);
            pbuf[pos] = ((unsigned)s << 8) | (unsigned)(d & 255);
        }
    }
}

// p2: per-bucket final CSR: 256-bin LDS hist -> row_start/dis, LDS-cursor placement
__global__ __launch_bounds__(256) void p2_csr(const unsigned int* __restrict__ pbuf,
                                              const int* __restrict__ bbase,
                                              int N, int E,
                                              int* __restrict__ edges4,
                                              int* __restrict__ row_start,
                                              float* __restrict__ dis) {
    __shared__ int hist[256];
    __shared__ int cur[256];
    __shared__ int wsum[4];
    int k = blockIdx.x, t = threadIdx.x;
    int gbase = bbase[k], gend = bbase[k + 1];
    hist[t] = 0;
    __syncthreads();
    for (int p = gbase + t; p < gend; p += 256)
        atomicAdd(&hist[pbuf[p] & 255], 1);
    __syncthreads();
    int c = hist[t];
    int lane = t & 63, wid = t >> 6;
    int incl = c;
    #pragma unroll
    for (int off = 1; off < 64; off <<= 1) {
        int n = __shfl_up(incl, off, 64);
        if (lane >= off) incl += n;
    }
    if (lane == 63) wsum[wid] = incl;
    __syncthreads();
    int wbase = 0;
    #pragma unroll
    for (int w = 0; w < 4; ++w)
        if (w < wid) wbase += wsum[w];
    int excl = wbase + incl - c;
    int id = k * 256 + t;
    if (id < N) {
        row_start[id] = gbase + excl;
        dis[id] = rsqrtf((float)(c + 1));   // +1 self loop
    }
    if (k == 0 && t == 0) row_start[N] = E;
    cur[t] = gbase + excl;
    __syncthreads();
    for (int p = gbase + t; p < gend; p += 256) {
        unsigned rec = pbuf[p];
        int pos = atomicAdd(&cur[rec & 255], 1);
        edges4[pos] = (int)(rec >> 8);
    }
}

// ---------- W fragment prep: Ws[L][128][128] -> hi/lo bf16 fragment planes ----------
__global__ __launch_bounds__(256) void wprep_kernel(const float* __restrict__ Ws,
                                                    unsigned short* __restrict__ WHg,
                                                    unsigned short* __restrict__ WLg,
                                                    int total) {
    int g = blockIdx.x * 256 + threadIdx.x;
    if (g >= total) return;
    int l = g >> 11;         // layer
    int t = g & 2047;
    int s = t >> 9;
    int n = (t >> 6) & 7;
    int lane = t & 63;
    int kb = s * 32 + ((lane >> 4) << 2);
    int c  = n * 16 + (lane & 15);
    const float* W = Ws + (size_t)l * DF * DF;
    bf16x8 hi, lo;
    #pragma unroll
    for (int j = 0; j < 8; ++j) {
        int k = kb + (j & 3) + ((j >> 2) << 4);
        float w = W[k * DF + c];
        unsigned short h = f32_to_bf16_rne(w);
        hi[j] = (short)h;
        lo[j] = (short)f32_to_bf16_rne(w - bf16_to_f32(h));
    }
    *(bf16x8*)&WHg[(size_t)g * 8] = hi;
    *(bf16x8*)&WLg[(size_t)g * 8] = lo;
}

// ---------- MFMA split-bf16 GEMM with pre-scale epilogue ----------
// C_fp16[r][c] = ((relu?relu(A):A) @ W)[r][c] * dis[r]   (g = h*dis)
#define GBM 128
__global__ __launch_bounds__(256) void gemm_mfma(const float* __restrict__ A,
                                                 const unsigned short* __restrict__ WHg,
                                                 const unsigned short* __restrict__ WLg,
                                                 const float* __restrict__ dis,
                                                 _Float16* __restrict__ C,
                                                 int M, int relu) {
    int tid  = threadIdx.x;
    int wid  = tid >> 6;
    int lane = tid & 63;
    int l15  = lane & 15;
    int l4   = lane >> 4;
    size_t row0 = (size_t)blockIdx.x * GBM + wid * 32;

    f32x4 acc[2][8];
    #pragma unroll
    for (int tr = 0; tr < 2; ++tr)
        #pragma unroll
        for (int n = 0; n < 8; ++n) acc[tr][n] = (f32x4)(0.f);

    const float* Ar0 = A + (row0 + l15) * DF;
    const float* Ar1 = A + (row0 + 16 + l15) * DF;
    bool ok0 = (row0 + l15) < (size_t)M;
    bool ok1 = (row0 + 16 + l15) < (size_t)M;
    float4 zero = make_float4(0.f, 0.f, 0.f, 0.f);

    #pragma unroll
    for (int s = 0; s < 4; ++s) {
        int c0 = s * 32 + l4 * 4;
        float4 a00 = ok0 ? *(const float4*)&Ar0[c0]      : zero;
        float4 a01 = ok0 ? *(const float4*)&Ar0[c0 + 16] : zero;
        float4 a10 = ok1 ? *(const float4*)&Ar1[c0]      : zero;
        float4 a11 = ok1 ? *(const float4*)&Ar1[c0 + 16] : zero;
        if (relu) {
            a00 = f4_relu(a00); a01 = f4_relu(a01);
            a10 = f4_relu(a10); a11 = f4_relu(a11);
        }
        bf16x8 ah0, al0, ah1, al1;
        split8(a00, a01, ah0, al0);
        split8(a10, a11, ah1, al1);
        #pragma unroll
        for (int n = 0; n < 8; ++n) {
            size_t g = (size_t)((s * 8 + n) * 64 + lane) * 8;
            bf16x8 bh = *(const bf16x8*)&WHg[g];
            bf16x8 bl = *(const bf16x8*)&WLg[g];
            acc[0][n] = __builtin_amdgcn_mfma_f32_16x16x32_bf16(ah0, bh, acc[0][n], 0, 0, 0);
            acc[0][n] = __builtin_amdgcn_mfma_f32_16x16x32_bf16(ah0, bl, acc[0][n], 0, 0, 0);
            acc[0][n] = __builtin_amdgcn_mfma_f32_16x16x32_bf16(al0, bh, acc[0][n], 0, 0, 0);
            acc[1][n] = __builtin_amdgcn_mfma_f32_16x16x32_bf16(ah1, bh, acc[1][n], 0, 0, 0);
            acc[1][n] = __builtin_amdgcn_mfma_f32_16x16x32_bf16(ah1, bl, acc[1][n], 0, 0, 0);
            acc[1][n] = __builtin_amdgcn_mfma_f32_16x16x32_bf16(al1, bh, acc[1][n], 0, 0, 0);
        }
    }

    // C/D layout: col = n*16 + (lane&15), row = tr*16 + (lane>>4)*4 + q
    #pragma unroll
    for (int tr = 0; tr < 2; ++tr) {
        size_t rbase = row0 + tr * 16 + l4 * 4;
        #pragma unroll
        for (int q = 0; q < 4; ++q) {
            size_t r = rbase + q;
            if (r < (size_t)M) {
                float ds = dis[r];
                #pragma unroll
                for (int n = 0; n < 8; ++n)
                    C[r * DF + n * 16 + l15] = (_Float16)(acc[tr][n][q] * ds);
            }
        }
    }
}

// ---------- aggregation: out[i] = dis[i]*(g[i] + sum_e g[src_e]) + b ----------
template <int FINAL>
__global__ __launch_bounds__(256) void agg_kernel(const _Float16* __restrict__ g,
                                                  const int* __restrict__ edges4,
                                                  const int* __restrict__ row_start,
                                                  const float* __restrict__ dis,
                                                  const float* __restrict__ bias,
                                                  const float* __restrict__ Wf,
                                                  const float* __restrict__ bf,
                                                  float* __restrict__ out, int N) {
    int gid = blockIdx.x * 16 + (threadIdx.x >> 4);  // node
    int l8  = threadIdx.x & 15;                      // 8-feature slot
    if (gid >= N) return;
    const h16x8* gv = (const h16x8*)g;               // 16 per row
    float acc[8];
    {
        h16x8 self = gv[(size_t)gid * 16 + l8];
        #pragma unroll
        for (int j = 0; j < 8; ++j) acc[j] = (float)self[j];
    }
    int s = row_start[gid], e = row_start[gid + 1];
    int p = s;
    for (; p + 4 <= e; p += 4) {
        int s0 = edges4[p];
        int s1 = edges4[p + 1];
        int s2 = edges4[p + 2];
        int s3 = edges4[p + 3];
        h16x8 v0 = gv[(size_t)s0 * 16 + l8];
        h16x8 v1 = gv[(size_t)s1 * 16 + l8];
        h16x8 v2 = gv[(size_t)s2 * 16 + l8];
        h16x8 v3 = gv[(size_t)s3 * 16 + l8];
        #pragma unroll
        for (int j = 0; j < 8; ++j)
            acc[j] += (float)v0[j] + (float)v1[j] + (float)v2[j] + (float)v3[j];
    }
    for (; p < e; ++p) {
        h16x8 v = gv[(size_t)edges4[p] * 16 + l8];
        #pragma unroll
        for (int j = 0; j < 8; ++j) acc[j] += (float)v[j];
    }
    float d = dis[gid];
    if (FINAL) {
        float pr = 0.f;
        #pragma unroll
        for (int j = 0; j < 8; ++j) {
            float v = fmaxf(acc[j] * d + bias[l8 * 8 + j], 0.f);
            pr += v * Wf[l8 * 8 + j];
        }
        #pragma unroll
        for (int off = 8; off > 0; off >>= 1) pr += __shfl_xor(pr, off, 16);
        if (l8 == 0) out[gid] = pr + bf[0];
    } else {
        float4 o0, o1;
        o0.x = acc[0] * d + bias[l8 * 8 + 0];
        o0.y = acc[1] * d + bias[l8 * 8 + 1];
        o0.z = acc[2] * d + bias[l8 * 8 + 2];
        o0.w = acc[3] * d + bias[l8 * 8 + 3];
        o1.x = acc[4] * d + bias[l8 * 8 + 4];
        o1.y = acc[5] * d + bias[l8 * 8 + 5];
        o1.z = acc[6] * d + bias[l8 * 8 + 6];
        o1.w = acc[7] * d + bias[l8 * 8 + 7];
        float4* op = (float4*)&out[(size_t)gid * DF + l8 * 8];
        op[0] = o0;
        op[1] = o1;
    }
}

extern "C" void kernel_launch(void* const* d_in, const int* in_sizes, int n_in,
                              void* d_out, int out_size, void* d_ws, size_t ws_size,
                              hipStream_t stream) {
    const float* x  = (const float*)d_in[0];
    const int*   ei = (const int*)d_in[1];
    const float* Ws = (const float*)d_in[2];
    const float* bs = (const float*)d_in[3];
    const float* Wf = (const float*)d_in[4];
    const float* bf = (const float*)d_in[5];
    float* out = (float*)d_out;

    int N = in_sizes[0] / DF;
    int E = in_sizes[1] / 2;
    int L = in_sizes[2] / (DF * DF);

    int NBUK  = (N + 255) >> 8;        // buckets of 256 nodes (391)
    int NBUKP = NBUK + 1;              // padded row
    int NBLK  = (E + EB - 1) / EB;     // radix blocks (391)

    char* p = (char*)d_ws;
    auto alloc = [&](size_t bytes) {
        char* r = p;
        p += (bytes + 255) & ~(size_t)255;
        return r;
    };
    int*   row_start = (int*)alloc((size_t)(N + 1) * 4);
    float* dis       = (float*)alloc((size_t)N * 4);
    int*   edges4    = (int*)alloc((size_t)E * 4);
    unsigned int* pbuf = (unsigned int*)alloc((size_t)E * 4);
    int*   parthist  = (int*)alloc((size_t)NBLK * NBUKP * 4);
    int*   btotal    = (int*)alloc((size_t)(NBUK + 1) * 4);
    _Float16* bufG   = (_Float16*)alloc((size_t)N * DF * 2);  // g = h*dis, fp16
    float* bufB      = (float*)alloc((size_t)N * DF * 4);     // fp32 agg output
    unsigned short* WHg = (unsigned short*)alloc((size_t)L * 2048 * 8 * 2);
    unsigned short* WLg = (unsigned short*)alloc((size_t)L * 2048 * 8 * 2);

    int WT = L * 2048;

    wprep_kernel<<<(WT + 255) / 256, 256, 0, stream>>>(Ws, WHg, WLg, WT);
    p1a_hist<<<NBLK, 256, 0, stream>>>(ei, E, NBUKP, parthist);
    colscan_kernel<<<NBUK, 256, 0, stream>>>(parthist, NBLK, NBUKP, btotal);
    scan_offsets_kernel<<<1, 1024, 0, stream>>>(btotal, NBUK, &btotal[NBUK]);
    p1c_scatter<<<NBLK, 256, 0, stream>>>(ei, E, NBUK, NBUKP, parthist, btotal, pbuf);
    p2_csr<<<NBUK, 256, 0, stream>>>(pbuf, btotal, N, E, edges4, row_start, dis);

    const float* hin = x;
    for (int l = 0; l < L; ++l) {
        gemm_mfma<<<(N + GBM - 1) / GBM, 256, 0, stream>>>(
            hin, WHg + (size_t)l * 16384, WLg + (size_t)l * 16384, dis, bufG, N, l > 0);
        if (l == L - 1) {
            agg_kernel<1><<<(N + 15) / 16, 256, 0, stream>>>(bufG, edges4, row_start, dis,
                                                             bs + (size_t)l * DF, Wf, bf, out, N);
        } else {
            agg_kernel<0><<<(N + 15) / 16, 256, 0, stream>>>(bufG, edges4, row_start, dis,
                                                             bs + (size_t)l * DF, nullptr, nullptr,
                                                             bufB, N);
            hin = bufB;
        }
    }
}